// Round 4
// baseline (899.281 us; speedup 1.0000x reference)
//
#include <hip/hip_runtime.h>
#include <hip/hip_bf16.h>
#include <math.h>

typedef __bf16 bf16_t;
typedef bf16_t bf16x8 __attribute__((ext_vector_type(8)));
typedef bf16_t bf16x4 __attribute__((ext_vector_type(4)));
typedef float  f32x4  __attribute__((ext_vector_type(4)));

#define AS1(p) ((__attribute__((address_space(1))) void*)(p))
#define AS3(p) ((__attribute__((address_space(3))) void*)(p))

// ---------------------------------------------------------------- converts
__global__ void convert_f32_bf16(const float* __restrict__ in, bf16_t* __restrict__ out)
{
    int i = blockIdx.x * 256 + threadIdx.x;
    float4 v = ((const float4*)in)[i];
    bf16x4 o;
    o[0] = (bf16_t)v.x; o[1] = (bf16_t)v.y; o[2] = (bf16_t)v.z; o[3] = (bf16_t)v.w;
    ((bf16x4*)out)[i] = o;
}

// W: [K][N] fp32 row-major  ->  Wt: [N][K] bf16 row-major
__global__ void transpose_convert(const float* __restrict__ W, bf16_t* __restrict__ Wt,
                                  int K, int N)
{
    __shared__ float tile[32][33];
    const int n0 = blockIdx.x * 32;
    const int k0 = blockIdx.y * 32;
    const int r = threadIdx.x >> 5;
    const int c = threadIdx.x & 31;
    #pragma unroll
    for (int i = 0; i < 32; i += 8)
        tile[r + i][c] = W[(size_t)(k0 + r + i) * N + n0 + c];
    __syncthreads();
    #pragma unroll
    for (int i = 0; i < 32; i += 8)
        Wt[(size_t)(n0 + r + i) * K + k0 + c] = (bf16_t)tile[c][r + i];
}

// ---------------------------------------------------------------- GEMM (m97 structure)
// C[M][N] = A[M][K] @ Bt[N][K]^T ; A,Bt bf16 ; 128x128 tile, BK=32, 256 thr / 4 waves
template <typename OutT>
__global__ __launch_bounds__(256)
void gemm_bt_128(const bf16_t* __restrict__ A, const bf16_t* __restrict__ Bt,
                 OutT* __restrict__ C, int M, int N, int K)
{
    __shared__ bf16_t As[128 * 32];
    __shared__ bf16_t Bs[128 * 32];
    const int t    = threadIdx.x;
    const int lane = t & 63;
    const int wave = t >> 6;
    const int m0 = blockIdx.x * 128;
    const int n0 = blockIdx.y * 128;
    const int wm = (wave & 1) * 64;
    const int wn = (wave >> 1) * 64;
    const int lm = lane & 15;
    const int lq = lane >> 4;

    f32x4 acc[4][4] = {};

    const int chunk0 = wave * 64 + lane;          // 0..255
    const int r0 = chunk0 >> 2, c0 = (chunk0 & 3) * 8;
    const int chunk1 = 256 + chunk0;              // 256..511
    const int r1 = chunk1 >> 2, c1 = (chunk1 & 3) * 8;

    const bf16_t* Ag0 = A  + (size_t)(m0 + r0) * K + c0;
    const bf16_t* Ag1 = A  + (size_t)(m0 + r1) * K + c1;
    const bf16_t* Bg0 = Bt + (size_t)(n0 + r0) * K + c0;
    const bf16_t* Bg1 = Bt + (size_t)(n0 + r1) * K + c1;
    bf16_t* As0 = As + (wave * 64) * 8;           // wave-uniform LDS bases
    bf16_t* As1 = As + (256 + wave * 64) * 8;
    bf16_t* Bs0 = Bs + (wave * 64) * 8;
    bf16_t* Bs1 = Bs + (256 + wave * 64) * 8;

    for (int k0 = 0; k0 < K; k0 += 32) {
        __syncthreads();
        __builtin_amdgcn_global_load_lds(AS1(Ag0 + k0), AS3(As0), 16, 0, 0);
        __builtin_amdgcn_global_load_lds(AS1(Ag1 + k0), AS3(As1), 16, 0, 0);
        __builtin_amdgcn_global_load_lds(AS1(Bg0 + k0), AS3(Bs0), 16, 0, 0);
        __builtin_amdgcn_global_load_lds(AS1(Bg1 + k0), AS3(Bs1), 16, 0, 0);
        __syncthreads();

        bf16x8 af[4], bb[4];
        #pragma unroll
        for (int mt = 0; mt < 4; ++mt)
            af[mt] = *(const bf16x8*)(As + (wm + mt * 16 + lm) * 32 + lq * 8);
        #pragma unroll
        for (int nt = 0; nt < 4; ++nt)
            bb[nt] = *(const bf16x8*)(Bs + (wn + nt * 16 + lm) * 32 + lq * 8);
        #pragma unroll
        for (int mt = 0; mt < 4; ++mt)
            #pragma unroll
            for (int nt = 0; nt < 4; ++nt)
                acc[mt][nt] = __builtin_amdgcn_mfma_f32_16x16x32_bf16(
                    af[mt], bb[nt], acc[mt][nt], 0, 0, 0);
    }

    #pragma unroll
    for (int mt = 0; mt < 4; ++mt) {
        #pragma unroll
        for (int nt = 0; nt < 4; ++nt) {
            const int row = m0 + wm + mt * 16 + lq * 4;
            const int col = n0 + wn + nt * 16 + lm;
            #pragma unroll
            for (int r = 0; r < 4; ++r) {
                float v = acc[mt][nt][r];
                if constexpr (sizeof(OutT) == 2)
                    C[(size_t)(row + r) * N + col] = (OutT)(bf16_t)v;
                else
                    C[(size_t)(row + r) * N + col] = v;
            }
        }
    }
}

// ---------------------------------------------------------------- RoPE (in-place on QKV) + k output
// QKV: [S][6144] bf16 ; cols 0..4095 = Q (32 heads), 4096..5119 = K (8 kv heads)
__global__ void rope_qk(bf16_t* __restrict__ QKV, float* __restrict__ k_out, int S)
{
    int idx  = blockIdx.x * 256 + threadIdx.x;   // over S*64
    int d    = idx & 63;
    int s    = idx >> 6;
    int head = blockIdx.y;                       // 0..39 (0..31 Q, 32..39 K)
    float ang = (float)s * exp2f((float)d * -0.20762050593f);  // log2(10000)/64
    float sn, cs;
    sincosf(ang, &sn, &cs);
    int col = head < 32 ? head * 128 : 4096 + (head - 32) * 128;
    bf16_t* p = QKV + (size_t)s * 6144 + col;
    float x1 = (float)p[d], x2 = (float)p[d + 64];
    float y1 = x1 * cs - x2 * sn;
    float y2 = x2 * cs + x1 * sn;
    p[d]      = (bf16_t)y1;
    p[d + 64] = (bf16_t)y2;
    if (head >= 32) {
        int g = head - 32;
        #pragma unroll
        for (int j = 0; j < 4; ++j) {            // repeat_interleave x4
            float* kb = k_out + ((size_t)(g * 4 + j) * S + s) * 128;
            kb[d]      = y1;
            kb[d + 64] = y2;
        }
    }
}

// ---------------------------------------------------------------- v output + V^T build
// QKV cols 5120..6143 = V. v_out: [32][S][128] fp32 ; Vt: [1024][S] bf16
__global__ void v_finish(const bf16_t* __restrict__ QKV, float* __restrict__ v_out,
                         bf16_t* __restrict__ Vt, int S)
{
    __shared__ bf16_t tl[32][33];
    const int s0  = blockIdx.x * 32;
    const int gd0 = blockIdx.y * 32;
    const int r = threadIdx.x >> 5;
    const int c = threadIdx.x & 31;
    #pragma unroll
    for (int i = 0; i < 32; i += 8) {
        int s = s0 + r + i;
        bf16_t v = QKV[(size_t)s * 6144 + 5120 + gd0 + c];
        tl[r + i][c] = v;
        int gd = gd0 + c;
        int g = gd >> 7, d = gd & 127;
        float vf = (float)v;
        #pragma unroll
        for (int j = 0; j < 4; ++j)
            v_out[((size_t)(g * 4 + j) * S + s) * 128 + d] = vf;
    }
    __syncthreads();
    #pragma unroll
    for (int i = 0; i < 32; i += 8)
        Vt[(size_t)(gd0 + r + i) * S + s0 + c] = tl[c][r + i];
}

// ---------------------------------------------------------------- fragment packer
// Repack K (rope'd, from QKV) and V^T (from Vt) into MFMA-fragment-contiguous
// layouts so the attention inner loop issues only fully-coalesced 1KB loads.
__global__ void pack_frags(const bf16_t* __restrict__ QKV, const bf16_t* __restrict__ Vt,
                           bf16_t* __restrict__ Kfrag, bf16_t* __restrict__ Vfrag, int S)
{
    const int b  = blockIdx.x;        // 256 tiles: g = b>>5, kt = b&31
    const int g  = b >> 5, kt = b & 31;
    const int t  = threadIdx.x;
    bf16x8* Kf = (bf16x8*)Kfrag + (size_t)b * 1024;
    bf16x8* Vf = (bf16x8*)Vfrag + (size_t)b * 1024;
    #pragma unroll
    for (int i = 0; i < 4; ++i) {     // K: 1024 granule slots
        int slot = i * 256 + t;
        int f = slot >> 6, l = slot & 63;
        int kk = f >> 2, nt = f & 3, lm = l & 15, lq = l >> 4;
        Kf[slot] = *(const bf16x8*)(QKV + (size_t)(kt * 64 + nt * 16 + lm) * 6144
                                    + 4096 + g * 128 + kk * 32 + lq * 8);
    }
    #pragma unroll
    for (int i = 0; i < 4; ++i) {     // V: 1024 granule slots
        int slot = i * 256 + t;
        int f = slot >> 6, l = slot & 63;
        int kk = f >> 3, nt = f & 7, lm = l & 15, lq = l >> 4;
        Vf[slot] = *(const bf16x8*)(Vt + (size_t)(g * 128 + nt * 16 + lm) * S
                                    + kt * 64 + kk * 32 + lq * 8);
    }
}

// ---------------------------------------------------------------- flash attention (causal, split-K x4)
// One block per (head, 32 q-rows); FOUR waves split the key-tile range
// (wave w handles kt = w, w+4, ...), each with private online-softmax state.
// LDS combine at the end: per-row global max -> factors -> sequential f32
// accumulate -> wave 3 writes O. 4x shorter critical path, 2x resident waves.
__global__ __launch_bounds__(256, 4)
void attn_fwd(const bf16_t* __restrict__ QKV,
              const bf16_t* __restrict__ Kfrag, const bf16_t* __restrict__ Vfrag,
              bf16_t* __restrict__ O, int S)
{
    const int task = blockIdx.x;                 // 2048 tasks
    const int h    = task & 31;
    const int c    = 63 - (task >> 5);           // q-chunk, heavy-first dispatch
    const int g    = h >> 2;
    const int wave = threadIdx.x >> 6;           // 0..3 key-split
    const int lane = threadIdx.x & 63;
    const int lm   = lane & 15;
    const int lq   = lane >> 4;
    const int q0   = c * 32;

    // LDS: per-wave P buffers (4 x 32x72 bf16 = 18432 B), aliased after the
    // K-loop by the combine region: Cb[32][132] f32 (16896 B) + ml[4][2][32] (1024 B)
    __shared__ __align__(16) char smem[18432];
    bf16_t* P  = (bf16_t*)smem + wave * (32 * 72);
    float*  Cb = (float*)smem;                   // [32][132]
    float*  ml = (float*)(smem + 16896);         // [w][{m,l}][row]

    // Q fragments resident in registers (A-layout): 2 m-tiles x 4 k-chunks
    bf16x8 aq[2][4];
    #pragma unroll
    for (int mi = 0; mi < 2; ++mi) {
        const bf16_t* qrow = QKV + (size_t)(q0 + mi * 16 + lm) * 6144 + h * 128;
        #pragma unroll
        for (int kk = 0; kk < 4; ++kk)
            aq[mi][kk] = *(const bf16x8*)(qrow + kk * 32 + lq * 8);
    }

    f32x4 acc[2][8] = {};
    float mrow[2][4], lrow[2][4];
    #pragma unroll
    for (int mi = 0; mi < 2; ++mi)
        #pragma unroll
        for (int r = 0; r < 4; ++r) { mrow[mi][r] = -3.0e38f; lrow[mi][r] = 0.f; }
    const float scale = 0.08838834764831845f;    // 1/sqrt(128)

    const int nkt = (q0 >> 6) + 1;

    for (int kt = wave; kt < nkt; kt += 4) {
        const int k0 = kt * 64;
        const bf16x8* Kf = (const bf16x8*)Kfrag + ((size_t)(g * 32 + kt) << 10);
        const bf16x8* Vf = (const bf16x8*)Vfrag + ((size_t)(g * 32 + kt) << 10);

        // K fragments: coalesced
        bf16x8 bk[4][4];                          // [kk][nt]
        #pragma unroll
        for (int kk = 0; kk < 4; ++kk)
            #pragma unroll
            for (int nt = 0; nt < 4; ++nt)
                bk[kk][nt] = Kf[(kk * 4 + nt) * 64 + lane];

        f32x4 sc[2][4] = {};
        #pragma unroll
        for (int kk = 0; kk < 4; ++kk)
            #pragma unroll
            for (int nt = 0; nt < 4; ++nt)
                #pragma unroll
                for (int mi = 0; mi < 2; ++mi)
                    sc[mi][nt] = __builtin_amdgcn_mfma_f32_16x16x32_bf16(
                        aq[mi][kk], bk[kk][nt], sc[mi][nt], 0, 0, 0);

        // V^T fragments: issue now so they overlap the softmax VALU work
        bf16x8 bv[2][8];                          // [kk][nt]
        #pragma unroll
        for (int kk = 0; kk < 2; ++kk)
            #pragma unroll
            for (int nt = 0; nt < 8; ++nt)
                bv[kk][nt] = Vf[(kk * 8 + nt) * 64 + lane];

        #pragma unroll
        for (int mi = 0; mi < 2; ++mi)
            #pragma unroll
            for (int nt = 0; nt < 4; ++nt)
                #pragma unroll
                for (int r = 0; r < 4; ++r)
                    sc[mi][nt][r] *= scale;

        if (kt == nkt - 1) {                      // causal mask on final tile
            #pragma unroll
            for (int mi = 0; mi < 2; ++mi)
                #pragma unroll
                for (int nt = 0; nt < 4; ++nt) {
                    int col = k0 + nt * 16 + lm;
                    #pragma unroll
                    for (int r = 0; r < 4; ++r) {
                        int row = q0 + mi * 16 + lq * 4 + r;
                        if (col > row) sc[mi][nt][r] = -3.0e38f;
                    }
                }
        }

        // online softmax (row lives across the 16 lm-lanes of an lq-group)
        #pragma unroll
        for (int mi = 0; mi < 2; ++mi) {
            float tmax[4];
            #pragma unroll
            for (int r = 0; r < 4; ++r)
                tmax[r] = fmaxf(fmaxf(sc[mi][0][r], sc[mi][1][r]),
                                fmaxf(sc[mi][2][r], sc[mi][3][r]));
            #pragma unroll
            for (int off = 1; off < 16; off <<= 1)
                #pragma unroll
                for (int r = 0; r < 4; ++r)
                    tmax[r] = fmaxf(tmax[r], __shfl_xor(tmax[r], off));

            float alpha[4];
            #pragma unroll
            for (int r = 0; r < 4; ++r) {
                float mn = fmaxf(mrow[mi][r], tmax[r]);
                alpha[r] = __expf(mrow[mi][r] - mn);
                mrow[mi][r] = mn;
            }
            float rsum[4] = {0.f, 0.f, 0.f, 0.f};
            #pragma unroll
            for (int nt = 0; nt < 4; ++nt)
                #pragma unroll
                for (int r = 0; r < 4; ++r) {
                    float p = __expf(sc[mi][nt][r] - mrow[mi][r]);
                    sc[mi][nt][r] = p;
                    rsum[r] += p;
                }
            #pragma unroll
            for (int off = 1; off < 16; off <<= 1)
                #pragma unroll
                for (int r = 0; r < 4; ++r)
                    rsum[r] += __shfl_xor(rsum[r], off);
            #pragma unroll
            for (int r = 0; r < 4; ++r)
                lrow[mi][r] = lrow[mi][r] * alpha[r] + rsum[r];
            #pragma unroll
            for (int nt = 0; nt < 8; ++nt)
                #pragma unroll
                for (int r = 0; r < 4; ++r)
                    acc[mi][nt][r] *= alpha[r];

            // P: C-layout -> LDS (per-wave buffer, wave-internal)
            #pragma unroll
            for (int nt = 0; nt < 4; ++nt)
                #pragma unroll
                for (int r = 0; r < 4; ++r)
                    P[(mi * 16 + lq * 4 + r) * 72 + nt * 16 + lm] = (bf16_t)sc[mi][nt][r];
        }

        // P: LDS -> A-layout (wave-internal; compiler inserts lgkmcnt wait)
        bf16x8 ap[2][2];
        #pragma unroll
        for (int mi = 0; mi < 2; ++mi)
            #pragma unroll
            for (int kk = 0; kk < 2; ++kk)
                ap[mi][kk] = *(const bf16x8*)(P + (mi * 16 + lm) * 72 + kk * 32 + lq * 8);

        #pragma unroll
        for (int kk = 0; kk < 2; ++kk)
            #pragma unroll
            for (int nt = 0; nt < 8; ++nt)
                #pragma unroll
                for (int mi = 0; mi < 2; ++mi)
                    acc[mi][nt] = __builtin_amdgcn_mfma_f32_16x16x32_bf16(
                        ap[mi][kk], bv[kk][nt], acc[mi][nt], 0, 0, 0);
    }

    // -------- cross-wave combine --------
    // publish per-row m,l (lanes lm==0 cover rows via lq,r)
    if (lm == 0) {
        #pragma unroll
        for (int mi = 0; mi < 2; ++mi)
            #pragma unroll
            for (int r = 0; r < 4; ++r) {
                int lr = mi * 16 + lq * 4 + r;
                ml[(wave * 2 + 0) * 32 + lr] = mrow[mi][r];
                ml[(wave * 2 + 1) * 32 + lr] = lrow[mi][r];
            }
    }
    __syncthreads();

    float fac[2][4], linv[2][4];
    #pragma unroll
    for (int mi = 0; mi < 2; ++mi)
        #pragma unroll
        for (int r = 0; r < 4; ++r) {
            int lr = mi * 16 + lq * 4 + r;
            float m0 = ml[0 * 32 + lr], m1 = ml[2 * 32 + lr];
            float m2 = ml[4 * 32 + lr], m3 = ml[6 * 32 + lr];
            float mg = fmaxf(fmaxf(m0, m1), fmaxf(m2, m3));
            float ls = ml[1 * 32 + lr] * __expf(m0 - mg)
                     + ml[3 * 32 + lr] * __expf(m1 - mg)
                     + ml[5 * 32 + lr] * __expf(m2 - mg)
                     + ml[7 * 32 + lr] * __expf(m3 - mg);
            fac[mi][r]  = __expf(mrow[mi][r] - mg);
            linv[mi][r] = 1.0f / ls;
        }

    // sequential f32 accumulation: waves 0..2 into Cb, wave 3 reads+adds+writes O
    for (int w = 0; w < 3; ++w) {
        if (wave == w) {
            #pragma unroll
            for (int mi = 0; mi < 2; ++mi)
                #pragma unroll
                for (int nt = 0; nt < 8; ++nt)
                    #pragma unroll
                    for (int r = 0; r < 4; ++r) {
                        int lr = mi * 16 + lq * 4 + r;
                        int col = nt * 16 + lm;
                        float v = acc[mi][nt][r] * fac[mi][r];
                        if (w == 0) Cb[lr * 132 + col] = v;
                        else        Cb[lr * 132 + col] += v;
                    }
        }
        __syncthreads();
    }
    if (wave == 3) {
        #pragma unroll
        for (int mi = 0; mi < 2; ++mi)
            #pragma unroll
            for (int nt = 0; nt < 8; ++nt)
                #pragma unroll
                for (int r = 0; r < 4; ++r) {
                    int lr = mi * 16 + lq * 4 + r;
                    int col = nt * 16 + lm;
                    float v = Cb[lr * 132 + col] + acc[mi][nt][r] * fac[mi][r];
                    O[(size_t)(q0 + lr) * 4096 + h * 128 + col] =
                        (bf16_t)(v * linv[mi][r]);
                }
    }
}

// ---------------------------------------------------------------- launch
extern "C" void kernel_launch(void* const* d_in, const int* in_sizes, int n_in,
                              void* d_out, int out_size, void* d_ws, size_t ws_size,
                              hipStream_t stream)
{
    const float* hidden = (const float*)d_in[0];
    const float* Wq = (const float*)d_in[1];
    const float* Wk = (const float*)d_in[2];
    const float* Wv = (const float*)d_in[3];
    const float* Wo = (const float*)d_in[4];

    const int S = 2048, H = 4096, KV = 1024, NQKV = 6144;

    // workspace layout (total ~140 MB)
    char* ws = (char*)d_ws;
    bf16_t* hid_b  = (bf16_t*)(ws);                         // S*H bf16      = 16 MB
    bf16_t* Wqkv_t = (bf16_t*)(ws + (size_t)(16u  << 20));  // 6144*4096 bf16= 48 MB
    bf16_t* Wo_t   = (bf16_t*)(ws + (size_t)(64u  << 20));  // 4096*4096 bf16= 32 MB
    bf16_t* QKV    = (bf16_t*)(ws + (size_t)(96u  << 20));  // S*6144 bf16   = 24 MB
    bf16_t* Vt     = (bf16_t*)(ws + (size_t)(120u << 20));  // 1024*S bf16   =  4 MB
    bf16_t* attn   = (bf16_t*)(ws + (size_t)(124u << 20));  // S*H bf16      = 16 MB
    // Kfrag/Vfrag reuse hid_b's region (dead after the QKV GEMM): 4 MB + 4 MB
    bf16_t* Kfrag  = (bf16_t*)(ws);
    bf16_t* Vfrag  = (bf16_t*)(ws + (size_t)(4u << 20));

    float* out_o = (float*)d_out;                 // [S][H]
    float* out_k = out_o + (size_t)S * H;         // [32][S][128]
    float* out_v = out_k + (size_t)32 * S * 128;  // [32][S][128]

    convert_f32_bf16<<<S * H / 4 / 256, 256, 0, stream>>>(hidden, hid_b);
    transpose_convert<<<dim3(H / 32, H / 32), 256, 0, stream>>>(Wq, Wqkv_t, H, H);
    transpose_convert<<<dim3(KV / 32, H / 32), 256, 0, stream>>>(Wk, Wqkv_t + (size_t)4096 * H, H, KV);
    transpose_convert<<<dim3(KV / 32, H / 32), 256, 0, stream>>>(Wv, Wqkv_t + (size_t)5120 * H, H, KV);
    transpose_convert<<<dim3(H / 32, H / 32), 256, 0, stream>>>(Wo, Wo_t, H, H);

    gemm_bt_128<bf16_t><<<dim3(S / 128, NQKV / 128), 256, 0, stream>>>(hid_b, Wqkv_t, QKV, S, NQKV, H);

    rope_qk<<<dim3(S * 64 / 256, 40), 256, 0, stream>>>(QKV, out_k, S);
    v_finish<<<dim3(S / 32, KV / 32), 256, 0, stream>>>(QKV, out_v, Vt, S);
    pack_frags<<<256, 256, 0, stream>>>(QKV, Vt, Kfrag, Vfrag, S);

    attn_fwd<<<2048, 256, 0, stream>>>(QKV, Kfrag, Vfrag, attn, S);

    gemm_bt_128<float><<<dim3(S / 128, H / 128), 256, 0, stream>>>(attn, Wo_t, out_o, S, H, H);
}

// Round 6
// 606.909 us; speedup vs baseline: 1.4817x; 1.4817x over previous
//
#include <hip/hip_runtime.h>
#include <hip/hip_bf16.h>
#include <math.h>

typedef __bf16 bf16_t;
typedef bf16_t bf16x8 __attribute__((ext_vector_type(8)));
typedef bf16_t bf16x4 __attribute__((ext_vector_type(4)));
typedef float  f32x4  __attribute__((ext_vector_type(4)));

#define AS1(p) ((__attribute__((address_space(1))) void*)(p))
#define AS3(p) ((__attribute__((address_space(3))) void*)(p))

// ---------------------------------------------------------------- converts
__global__ void convert_f32_bf16(const float* __restrict__ in, bf16_t* __restrict__ out)
{
    int i = blockIdx.x * 256 + threadIdx.x;
    float4 v = ((const float4*)in)[i];
    bf16x4 o;
    o[0] = (bf16_t)v.x; o[1] = (bf16_t)v.y; o[2] = (bf16_t)v.z; o[3] = (bf16_t)v.w;
    ((bf16x4*)out)[i] = o;
}

// W: [K][N] fp32 row-major  ->  Wt: [N][K] bf16 row-major
__global__ void transpose_convert(const float* __restrict__ W, bf16_t* __restrict__ Wt,
                                  int K, int N)
{
    __shared__ float tile[32][33];
    const int n0 = blockIdx.x * 32;
    const int k0 = blockIdx.y * 32;
    const int r = threadIdx.x >> 5;
    const int c = threadIdx.x & 31;
    #pragma unroll
    for (int i = 0; i < 32; i += 8)
        tile[r + i][c] = W[(size_t)(k0 + r + i) * N + n0 + c];
    __syncthreads();
    #pragma unroll
    for (int i = 0; i < 32; i += 8)
        Wt[(size_t)(n0 + r + i) * K + k0 + c] = (bf16_t)tile[c][r + i];
}

// ---------------------------------------------------------------- GEMM (m97 structure)
// C[M][N] = A[M][K] @ Bt[N][K]^T ; A,Bt bf16 ; 128x128 tile, BK=32, 256 thr / 4 waves
template <typename OutT>
__global__ __launch_bounds__(256)
void gemm_bt_128(const bf16_t* __restrict__ A, const bf16_t* __restrict__ Bt,
                 OutT* __restrict__ C, int M, int N, int K)
{
    __shared__ bf16_t As[128 * 32];
    __shared__ bf16_t Bs[128 * 32];
    const int t    = threadIdx.x;
    const int lane = t & 63;
    const int wave = t >> 6;
    const int m0 = blockIdx.x * 128;
    const int n0 = blockIdx.y * 128;
    const int wm = (wave & 1) * 64;
    const int wn = (wave >> 1) * 64;
    const int lm = lane & 15;
    const int lq = lane >> 4;

    f32x4 acc[4][4] = {};

    const int chunk0 = wave * 64 + lane;          // 0..255
    const int r0 = chunk0 >> 2, c0 = (chunk0 & 3) * 8;
    const int chunk1 = 256 + chunk0;              // 256..511
    const int r1 = chunk1 >> 2, c1 = (chunk1 & 3) * 8;

    const bf16_t* Ag0 = A  + (size_t)(m0 + r0) * K + c0;
    const bf16_t* Ag1 = A  + (size_t)(m0 + r1) * K + c1;
    const bf16_t* Bg0 = Bt + (size_t)(n0 + r0) * K + c0;
    const bf16_t* Bg1 = Bt + (size_t)(n0 + r1) * K + c1;
    bf16_t* As0 = As + (wave * 64) * 8;           // wave-uniform LDS bases
    bf16_t* As1 = As + (256 + wave * 64) * 8;
    bf16_t* Bs0 = Bs + (wave * 64) * 8;
    bf16_t* Bs1 = Bs + (256 + wave * 64) * 8;

    for (int k0 = 0; k0 < K; k0 += 32) {
        __syncthreads();
        __builtin_amdgcn_global_load_lds(AS1(Ag0 + k0), AS3(As0), 16, 0, 0);
        __builtin_amdgcn_global_load_lds(AS1(Ag1 + k0), AS3(As1), 16, 0, 0);
        __builtin_amdgcn_global_load_lds(AS1(Bg0 + k0), AS3(Bs0), 16, 0, 0);
        __builtin_amdgcn_global_load_lds(AS1(Bg1 + k0), AS3(Bs1), 16, 0, 0);
        __syncthreads();

        bf16x8 af[4], bb[4];
        #pragma unroll
        for (int mt = 0; mt < 4; ++mt)
            af[mt] = *(const bf16x8*)(As + (wm + mt * 16 + lm) * 32 + lq * 8);
        #pragma unroll
        for (int nt = 0; nt < 4; ++nt)
            bb[nt] = *(const bf16x8*)(Bs + (wn + nt * 16 + lm) * 32 + lq * 8);
        #pragma unroll
        for (int mt = 0; mt < 4; ++mt)
            #pragma unroll
            for (int nt = 0; nt < 4; ++nt)
                acc[mt][nt] = __builtin_amdgcn_mfma_f32_16x16x32_bf16(
                    af[mt], bb[nt], acc[mt][nt], 0, 0, 0);
    }

    #pragma unroll
    for (int mt = 0; mt < 4; ++mt) {
        #pragma unroll
        for (int nt = 0; nt < 4; ++nt) {
            const int row = m0 + wm + mt * 16 + lq * 4;
            const int col = n0 + wn + nt * 16 + lm;
            #pragma unroll
            for (int r = 0; r < 4; ++r) {
                float v = acc[mt][nt][r];
                if constexpr (sizeof(OutT) == 2)
                    C[(size_t)(row + r) * N + col] = (OutT)(bf16_t)v;
                else
                    C[(size_t)(row + r) * N + col] = v;
            }
        }
    }
}

// ---------------------------------------------------------------- RoPE (in-place on QKV) + k output
// QKV: [S][6144] bf16 ; cols 0..4095 = Q (32 heads), 4096..5119 = K (8 kv heads)
__global__ void rope_qk(bf16_t* __restrict__ QKV, float* __restrict__ k_out, int S)
{
    int idx  = blockIdx.x * 256 + threadIdx.x;   // over S*64
    int d    = idx & 63;
    int s    = idx >> 6;
    int head = blockIdx.y;                       // 0..39 (0..31 Q, 32..39 K)
    float ang = (float)s * exp2f((float)d * -0.20762050593f);  // log2(10000)/64
    float sn, cs;
    sincosf(ang, &sn, &cs);
    int col = head < 32 ? head * 128 : 4096 + (head - 32) * 128;
    bf16_t* p = QKV + (size_t)s * 6144 + col;
    float x1 = (float)p[d], x2 = (float)p[d + 64];
    float y1 = x1 * cs - x2 * sn;
    float y2 = x2 * cs + x1 * sn;
    p[d]      = (bf16_t)y1;
    p[d + 64] = (bf16_t)y2;
    if (head >= 32) {
        int g = head - 32;
        #pragma unroll
        for (int j = 0; j < 4; ++j) {            // repeat_interleave x4
            float* kb = k_out + ((size_t)(g * 4 + j) * S + s) * 128;
            kb[d]      = y1;
            kb[d + 64] = y2;
        }
    }
}

// ---------------------------------------------------------------- v output + V^T build
// QKV cols 5120..6143 = V. v_out: [32][S][128] fp32 ; Vt: [1024][S] bf16
__global__ void v_finish(const bf16_t* __restrict__ QKV, float* __restrict__ v_out,
                         bf16_t* __restrict__ Vt, int S)
{
    __shared__ bf16_t tl[32][33];
    const int s0  = blockIdx.x * 32;
    const int gd0 = blockIdx.y * 32;
    const int r = threadIdx.x >> 5;
    const int c = threadIdx.x & 31;
    #pragma unroll
    for (int i = 0; i < 32; i += 8) {
        int s = s0 + r + i;
        bf16_t v = QKV[(size_t)s * 6144 + 5120 + gd0 + c];
        tl[r + i][c] = v;
        int gd = gd0 + c;
        int g = gd >> 7, d = gd & 127;
        float vf = (float)v;
        #pragma unroll
        for (int j = 0; j < 4; ++j)
            v_out[((size_t)(g * 4 + j) * S + s) * 128 + d] = vf;
    }
    __syncthreads();
    #pragma unroll
    for (int i = 0; i < 32; i += 8)
        Vt[(size_t)(gd0 + r + i) * S + s0 + c] = tl[c][r + i];
}

// ---------------------------------------------------------------- fragment packer
// Repack K (rope'd, from QKV) and V^T (from Vt) into MFMA-fragment-contiguous
// layouts so the attention inner loop issues only fully-coalesced 1KB loads.
__global__ void pack_frags(const bf16_t* __restrict__ QKV, const bf16_t* __restrict__ Vt,
                           bf16_t* __restrict__ Kfrag, bf16_t* __restrict__ Vfrag, int S)
{
    const int b  = blockIdx.x;        // 256 tiles: g = b>>5, kt = b&31
    const int g  = b >> 5, kt = b & 31;
    const int t  = threadIdx.x;
    bf16x8* Kf = (bf16x8*)Kfrag + (size_t)b * 1024;
    bf16x8* Vf = (bf16x8*)Vfrag + (size_t)b * 1024;
    #pragma unroll
    for (int i = 0; i < 4; ++i) {     // K: 1024 granule slots
        int slot = i * 256 + t;
        int f = slot >> 6, l = slot & 63;
        int kk = f >> 2, nt = f & 3, lm = l & 15, lq = l >> 4;
        Kf[slot] = *(const bf16x8*)(QKV + (size_t)(kt * 64 + nt * 16 + lm) * 6144
                                    + 4096 + g * 128 + kk * 32 + lq * 8);
    }
    #pragma unroll
    for (int i = 0; i < 4; ++i) {     // V: 1024 granule slots
        int slot = i * 256 + t;
        int f = slot >> 6, l = slot & 63;
        int kk = f >> 3, nt = f & 7, lm = l & 15, lq = l >> 4;
        Vf[slot] = *(const bf16x8*)(Vt + (size_t)(g * 128 + nt * 16 + lm) * S
                                    + kt * 64 + kk * 32 + lq * 8);
    }
}

// ---------------------------------------------------------------- flash attention (causal, split-K x4)
// One block per (head, 32 q-rows); FOUR waves split the key-tile range
// (wave w handles kt = w, w+4, ...), each with private online-softmax state.
// LDS combine at the end. __launch_bounds__(256, 2): unified VGPR+AGPR cap 256
// (R4's (256,4) capped at 128 and spilled -> 1.8 GB scratch traffic).
// LDS LIFETIME LEDGER (R5 NaN fix): ml gets its OWN region [18432,19456) --
// it is written by each wave right after its private K-loop, BEFORE the first
// __syncthreads(), so it must not overlap any wave's P buffer (R5 aliased it
// into wave 3's P; waves 0-2 finishing early clobbered wave 3's P with f32
// bit patterns whose high halves are bf16 NaN). Cb DOES alias P, but every
// Cb access is after the first __syncthreads() (all K-loops complete).
__global__ __launch_bounds__(256, 2)
void attn_fwd(const bf16_t* __restrict__ QKV,
              const bf16_t* __restrict__ Kfrag, const bf16_t* __restrict__ Vfrag,
              bf16_t* __restrict__ O, int S)
{
    const int task = blockIdx.x;                 // 2048 tasks
    const int h    = task & 31;
    const int c    = 63 - (task >> 5);           // q-chunk, heavy-first dispatch
    const int g    = h >> 2;
    const int wave = threadIdx.x >> 6;           // 0..3 key-split
    const int lane = threadIdx.x & 63;
    const int lm   = lane & 15;
    const int lq   = lane >> 4;
    const int q0   = c * 32;

    // [0,18432): per-wave P buffers (4 x 32x72 bf16), aliased by Cb[32][132] f32
    // after the first barrier. [18432,19456): ml[4][2][32] f32 (non-aliased).
    __shared__ __align__(16) char smem[19456];
    bf16_t* P  = (bf16_t*)smem + wave * (32 * 72);
    float*  Cb = (float*)smem;                   // [32][132]
    float*  ml = (float*)(smem + 18432);         // [w][{m,l}][row]

    // Q fragments resident in registers (A-layout): 2 m-tiles x 4 k-chunks
    bf16x8 aq[2][4];
    #pragma unroll
    for (int mi = 0; mi < 2; ++mi) {
        const bf16_t* qrow = QKV + (size_t)(q0 + mi * 16 + lm) * 6144 + h * 128;
        #pragma unroll
        for (int kk = 0; kk < 4; ++kk)
            aq[mi][kk] = *(const bf16x8*)(qrow + kk * 32 + lq * 8);
    }

    f32x4 acc[2][8] = {};
    float mrow[2][4], lrow[2][4];
    #pragma unroll
    for (int mi = 0; mi < 2; ++mi)
        #pragma unroll
        for (int r = 0; r < 4; ++r) { mrow[mi][r] = -3.0e38f; lrow[mi][r] = 0.f; }
    const float scale = 0.08838834764831845f;    // 1/sqrt(128)

    const int nkt = (q0 >> 6) + 1;

    for (int kt = wave; kt < nkt; kt += 4) {
        const int k0 = kt * 64;
        const bf16x8* Kf = (const bf16x8*)Kfrag + ((size_t)(g * 32 + kt) << 10);
        const bf16x8* Vf = (const bf16x8*)Vfrag + ((size_t)(g * 32 + kt) << 10);

        // K fragments: coalesced
        bf16x8 bk[4][4];                          // [kk][nt]
        #pragma unroll
        for (int kk = 0; kk < 4; ++kk)
            #pragma unroll
            for (int nt = 0; nt < 4; ++nt)
                bk[kk][nt] = Kf[(kk * 4 + nt) * 64 + lane];

        f32x4 sc[2][4] = {};
        #pragma unroll
        for (int kk = 0; kk < 4; ++kk)
            #pragma unroll
            for (int nt = 0; nt < 4; ++nt)
                #pragma unroll
                for (int mi = 0; mi < 2; ++mi)
                    sc[mi][nt] = __builtin_amdgcn_mfma_f32_16x16x32_bf16(
                        aq[mi][kk], bk[kk][nt], sc[mi][nt], 0, 0, 0);

        // V^T fragments: issue now so they overlap the softmax VALU work
        bf16x8 bv[2][8];                          // [kk][nt]
        #pragma unroll
        for (int kk = 0; kk < 2; ++kk)
            #pragma unroll
            for (int nt = 0; nt < 8; ++nt)
                bv[kk][nt] = Vf[(kk * 8 + nt) * 64 + lane];

        #pragma unroll
        for (int mi = 0; mi < 2; ++mi)
            #pragma unroll
            for (int nt = 0; nt < 4; ++nt)
                #pragma unroll
                for (int r = 0; r < 4; ++r)
                    sc[mi][nt][r] *= scale;

        if (kt == nkt - 1) {                      // causal mask on final tile
            #pragma unroll
            for (int mi = 0; mi < 2; ++mi)
                #pragma unroll
                for (int nt = 0; nt < 4; ++nt) {
                    int col = k0 + nt * 16 + lm;
                    #pragma unroll
                    for (int r = 0; r < 4; ++r) {
                        int row = q0 + mi * 16 + lq * 4 + r;
                        if (col > row) sc[mi][nt][r] = -3.0e38f;
                    }
                }
        }

        // online softmax (row lives across the 16 lm-lanes of an lq-group)
        #pragma unroll
        for (int mi = 0; mi < 2; ++mi) {
            float tmax[4];
            #pragma unroll
            for (int r = 0; r < 4; ++r)
                tmax[r] = fmaxf(fmaxf(sc[mi][0][r], sc[mi][1][r]),
                                fmaxf(sc[mi][2][r], sc[mi][3][r]));
            #pragma unroll
            for (int off = 1; off < 16; off <<= 1)
                #pragma unroll
                for (int r = 0; r < 4; ++r)
                    tmax[r] = fmaxf(tmax[r], __shfl_xor(tmax[r], off));

            float alpha[4];
            #pragma unroll
            for (int r = 0; r < 4; ++r) {
                float mn = fmaxf(mrow[mi][r], tmax[r]);
                alpha[r] = __expf(mrow[mi][r] - mn);
                mrow[mi][r] = mn;
            }
            float rsum[4] = {0.f, 0.f, 0.f, 0.f};
            #pragma unroll
            for (int nt = 0; nt < 4; ++nt)
                #pragma unroll
                for (int r = 0; r < 4; ++r) {
                    float p = __expf(sc[mi][nt][r] - mrow[mi][r]);
                    sc[mi][nt][r] = p;
                    rsum[r] += p;
                }
            #pragma unroll
            for (int off = 1; off < 16; off <<= 1)
                #pragma unroll
                for (int r = 0; r < 4; ++r)
                    rsum[r] += __shfl_xor(rsum[r], off);
            #pragma unroll
            for (int r = 0; r < 4; ++r)
                lrow[mi][r] = lrow[mi][r] * alpha[r] + rsum[r];
            #pragma unroll
            for (int nt = 0; nt < 8; ++nt)
                #pragma unroll
                for (int r = 0; r < 4; ++r)
                    acc[mi][nt][r] *= alpha[r];

            // P: C-layout -> LDS (per-wave buffer, wave-internal)
            #pragma unroll
            for (int nt = 0; nt < 4; ++nt)
                #pragma unroll
                for (int r = 0; r < 4; ++r)
                    P[(mi * 16 + lq * 4 + r) * 72 + nt * 16 + lm] = (bf16_t)sc[mi][nt][r];
        }

        // P: LDS -> A-layout (wave-internal; compiler inserts lgkmcnt wait)
        bf16x8 ap[2][2];
        #pragma unroll
        for (int mi = 0; mi < 2; ++mi)
            #pragma unroll
            for (int kk = 0; kk < 2; ++kk)
                ap[mi][kk] = *(const bf16x8*)(P + (mi * 16 + lm) * 72 + kk * 32 + lq * 8);

        #pragma unroll
        for (int kk = 0; kk < 2; ++kk)
            #pragma unroll
            for (int nt = 0; nt < 8; ++nt)
                #pragma unroll
                for (int mi = 0; mi < 2; ++mi)
                    acc[mi][nt] = __builtin_amdgcn_mfma_f32_16x16x32_bf16(
                        ap[mi][kk], bv[kk][nt], acc[mi][nt], 0, 0, 0);
    }

    // -------- cross-wave combine --------
    // publish per-row m,l into the DEDICATED ml region (safe pre-barrier:
    // each wave writes only its own slots, region overlaps no P buffer)
    if (lm == 0) {
        #pragma unroll
        for (int mi = 0; mi < 2; ++mi)
            #pragma unroll
            for (int r = 0; r < 4; ++r) {
                int lr = mi * 16 + lq * 4 + r;
                ml[(wave * 2 + 0) * 32 + lr] = mrow[mi][r];
                ml[(wave * 2 + 1) * 32 + lr] = lrow[mi][r];
            }
    }
    __syncthreads();

    float fac[2][4], linv[2][4];
    #pragma unroll
    for (int mi = 0; mi < 2; ++mi)
        #pragma unroll
        for (int r = 0; r < 4; ++r) {
            int lr = mi * 16 + lq * 4 + r;
            float m0 = ml[0 * 32 + lr], m1 = ml[2 * 32 + lr];
            float m2 = ml[4 * 32 + lr], m3 = ml[6 * 32 + lr];
            float mg = fmaxf(fmaxf(m0, m1), fmaxf(m2, m3));
            float ls = ml[1 * 32 + lr] * __expf(m0 - mg)
                     + ml[3 * 32 + lr] * __expf(m1 - mg)
                     + ml[5 * 32 + lr] * __expf(m2 - mg)
                     + ml[7 * 32 + lr] * __expf(m3 - mg);
            fac[mi][r]  = __expf(mrow[mi][r] - mg);
            linv[mi][r] = 1.0f / ls;
        }

    // sequential f32 accumulation: waves 0..2 into Cb, wave 3 reads+adds+writes O
    for (int w = 0; w < 3; ++w) {
        if (wave == w) {
            #pragma unroll
            for (int mi = 0; mi < 2; ++mi)
                #pragma unroll
                for (int nt = 0; nt < 8; ++nt)
                    #pragma unroll
                    for (int r = 0; r < 4; ++r) {
                        int lr = mi * 16 + lq * 4 + r;
                        int col = nt * 16 + lm;
                        float v = acc[mi][nt][r] * fac[mi][r];
                        if (w == 0) Cb[lr * 132 + col] = v;
                        else        Cb[lr * 132 + col] += v;
                    }
        }
        __syncthreads();
    }
    if (wave == 3) {
        #pragma unroll
        for (int mi = 0; mi < 2; ++mi)
            #pragma unroll
            for (int nt = 0; nt < 8; ++nt)
                #pragma unroll
                for (int r = 0; r < 4; ++r) {
                    int lr = mi * 16 + lq * 4 + r;
                    int col = nt * 16 + lm;
                    float v = Cb[lr * 132 + col] + acc[mi][nt][r] * fac[mi][r];
                    O[(size_t)(q0 + lr) * 4096 + h * 128 + col] =
                        (bf16_t)(v * linv[mi][r]);
                }
    }
}

// ---------------------------------------------------------------- launch
extern "C" void kernel_launch(void* const* d_in, const int* in_sizes, int n_in,
                              void* d_out, int out_size, void* d_ws, size_t ws_size,
                              hipStream_t stream)
{
    const float* hidden = (const float*)d_in[0];
    const float* Wq = (const float*)d_in[1];
    const float* Wk = (const float*)d_in[2];
    const float* Wv = (const float*)d_in[3];
    const float* Wo = (const float*)d_in[4];

    const int S = 2048, H = 4096, KV = 1024, NQKV = 6144;

    // workspace layout (total ~140 MB)
    char* ws = (char*)d_ws;
    bf16_t* hid_b  = (bf16_t*)(ws);                         // S*H bf16      = 16 MB
    bf16_t* Wqkv_t = (bf16_t*)(ws + (size_t)(16u  << 20));  // 6144*4096 bf16= 48 MB
    bf16_t* Wo_t   = (bf16_t*)(ws + (size_t)(64u  << 20));  // 4096*4096 bf16= 32 MB
    bf16_t* QKV    = (bf16_t*)(ws + (size_t)(96u  << 20));  // S*6144 bf16   = 24 MB
    bf16_t* Vt     = (bf16_t*)(ws + (size_t)(120u << 20));  // 1024*S bf16   =  4 MB
    bf16_t* attn   = (bf16_t*)(ws + (size_t)(124u << 20));  // S*H bf16      = 16 MB
    // Kfrag/Vfrag reuse hid_b's region (dead after the QKV GEMM): 4 MB + 4 MB
    bf16_t* Kfrag  = (bf16_t*)(ws);
    bf16_t* Vfrag  = (bf16_t*)(ws + (size_t)(4u << 20));

    float* out_o = (float*)d_out;                 // [S][H]
    float* out_k = out_o + (size_t)S * H;         // [32][S][128]
    float* out_v = out_k + (size_t)32 * S * 128;  // [32][S][128]

    convert_f32_bf16<<<S * H / 4 / 256, 256, 0, stream>>>(hidden, hid_b);
    transpose_convert<<<dim3(H / 32, H / 32), 256, 0, stream>>>(Wq, Wqkv_t, H, H);
    transpose_convert<<<dim3(KV / 32, H / 32), 256, 0, stream>>>(Wk, Wqkv_t + (size_t)4096 * H, H, KV);
    transpose_convert<<<dim3(KV / 32, H / 32), 256, 0, stream>>>(Wv, Wqkv_t + (size_t)5120 * H, H, KV);
    transpose_convert<<<dim3(H / 32, H / 32), 256, 0, stream>>>(Wo, Wo_t, H, H);

    gemm_bt_128<bf16_t><<<dim3(S / 128, NQKV / 128), 256, 0, stream>>>(hid_b, Wqkv_t, QKV, S, NQKV, H);

    rope_qk<<<dim3(S * 64 / 256, 40), 256, 0, stream>>>(QKV, out_k, S);
    v_finish<<<dim3(S / 32, KV / 32), 256, 0, stream>>>(QKV, out_v, Vt, S);
    pack_frags<<<256, 256, 0, stream>>>(QKV, Vt, Kfrag, Vfrag, S);

    attn_fwd<<<2048, 256, 0, stream>>>(QKV, Kfrag, Vfrag, attn, S);

    gemm_bt_128<float><<<dim3(S / 128, H / 128), 256, 0, stream>>>(attn, Wo_t, out_o, S, H, H);
}

// Round 7
// 596.040 us; speedup vs baseline: 1.5088x; 1.0182x over previous
//
#include <hip/hip_runtime.h>
#include <hip/hip_bf16.h>
#include <math.h>

typedef __bf16 bf16_t;
typedef bf16_t bf16x8 __attribute__((ext_vector_type(8)));
typedef bf16_t bf16x4 __attribute__((ext_vector_type(4)));
typedef float  f32x4  __attribute__((ext_vector_type(4)));

#define AS1(p) ((__attribute__((address_space(1))) void*)(p))
#define AS3(p) ((__attribute__((address_space(3))) void*)(p))

// ---------------------------------------------------------------- converts
__global__ void convert_f32_bf16(const float* __restrict__ in, bf16_t* __restrict__ out)
{
    int i = blockIdx.x * 256 + threadIdx.x;
    float4 v = ((const float4*)in)[i];
    bf16x4 o;
    o[0] = (bf16_t)v.x; o[1] = (bf16_t)v.y; o[2] = (bf16_t)v.z; o[3] = (bf16_t)v.w;
    ((bf16x4*)out)[i] = o;
}

// W: [K][N] fp32 row-major  ->  Wt: [N][K] bf16 row-major
__global__ void transpose_convert(const float* __restrict__ W, bf16_t* __restrict__ Wt,
                                  int K, int N)
{
    __shared__ float tile[32][33];
    const int n0 = blockIdx.x * 32;
    const int k0 = blockIdx.y * 32;
    const int r = threadIdx.x >> 5;
    const int c = threadIdx.x & 31;
    #pragma unroll
    for (int i = 0; i < 32; i += 8)
        tile[r + i][c] = W[(size_t)(k0 + r + i) * N + n0 + c];
    __syncthreads();
    #pragma unroll
    for (int i = 0; i < 32; i += 8)
        Wt[(size_t)(n0 + r + i) * K + k0 + c] = (bf16_t)tile[c][r + i];
}

// ---------------------------------------------------------------- GEMM (m97 structure + XCD swizzle)
// C[M][N] = A[M][K] @ Bt[N][K]^T ; A,Bt bf16 ; 128x128 tile, BK=32, 256 thr / 4 waves.
// T1 bijective chunked XCD swizzle (requires nwg % 8 == 0, true for both call
// sites: 768, 512): each XCD gets a contiguous bid-chunk -> contiguous n-range,
// so its L2 B-panel working set is nwg/8/gridX panels (6 resp. 4 MB) not all of B.
template <typename OutT>
__global__ __launch_bounds__(256)
void gemm_bt_128(const bf16_t* __restrict__ A, const bf16_t* __restrict__ Bt,
                 OutT* __restrict__ C, int M, int N, int K)
{
    __shared__ bf16_t As[128 * 32];
    __shared__ bf16_t Bs[128 * 32];
    const int t    = threadIdx.x;
    const int lane = t & 63;
    const int wave = t >> 6;

    const int nwg   = gridDim.x * gridDim.y;
    int bid = blockIdx.x + blockIdx.y * gridDim.x;
    const int chunk = nwg >> 3;                   // nwg % 8 == 0
    bid = (bid & 7) * chunk + (bid >> 3);
    const int m0 = (bid % gridDim.x) * 128;
    const int n0 = (bid / gridDim.x) * 128;

    const int wm = (wave & 1) * 64;
    const int wn = (wave >> 1) * 64;
    const int lm = lane & 15;
    const int lq = lane >> 4;

    f32x4 acc[4][4] = {};

    const int chunk0 = wave * 64 + lane;          // 0..255
    const int r0 = chunk0 >> 2, c0 = (chunk0 & 3) * 8;
    const int chunk1 = 256 + chunk0;              // 256..511
    const int r1 = chunk1 >> 2, c1 = (chunk1 & 3) * 8;

    const bf16_t* Ag0 = A  + (size_t)(m0 + r0) * K + c0;
    const bf16_t* Ag1 = A  + (size_t)(m0 + r1) * K + c1;
    const bf16_t* Bg0 = Bt + (size_t)(n0 + r0) * K + c0;
    const bf16_t* Bg1 = Bt + (size_t)(n0 + r1) * K + c1;
    bf16_t* As0 = As + (wave * 64) * 8;           // wave-uniform LDS bases
    bf16_t* As1 = As + (256 + wave * 64) * 8;
    bf16_t* Bs0 = Bs + (wave * 64) * 8;
    bf16_t* Bs1 = Bs + (256 + wave * 64) * 8;

    for (int k0 = 0; k0 < K; k0 += 32) {
        __syncthreads();
        __builtin_amdgcn_global_load_lds(AS1(Ag0 + k0), AS3(As0), 16, 0, 0);
        __builtin_amdgcn_global_load_lds(AS1(Ag1 + k0), AS3(As1), 16, 0, 0);
        __builtin_amdgcn_global_load_lds(AS1(Bg0 + k0), AS3(Bs0), 16, 0, 0);
        __builtin_amdgcn_global_load_lds(AS1(Bg1 + k0), AS3(Bs1), 16, 0, 0);
        __syncthreads();

        bf16x8 af[4], bb[4];
        #pragma unroll
        for (int mt = 0; mt < 4; ++mt)
            af[mt] = *(const bf16x8*)(As + (wm + mt * 16 + lm) * 32 + lq * 8);
        #pragma unroll
        for (int nt = 0; nt < 4; ++nt)
            bb[nt] = *(const bf16x8*)(Bs + (wn + nt * 16 + lm) * 32 + lq * 8);
        #pragma unroll
        for (int mt = 0; mt < 4; ++mt)
            #pragma unroll
            for (int nt = 0; nt < 4; ++nt)
                acc[mt][nt] = __builtin_amdgcn_mfma_f32_16x16x32_bf16(
                    af[mt], bb[nt], acc[mt][nt], 0, 0, 0);
    }

    #pragma unroll
    for (int mt = 0; mt < 4; ++mt) {
        #pragma unroll
        for (int nt = 0; nt < 4; ++nt) {
            const int row = m0 + wm + mt * 16 + lq * 4;
            const int col = n0 + wn + nt * 16 + lm;
            #pragma unroll
            for (int r = 0; r < 4; ++r) {
                float v = acc[mt][nt][r];
                if constexpr (sizeof(OutT) == 2)
                    C[(size_t)(row + r) * N + col] = (OutT)(bf16_t)v;
                else
                    C[(size_t)(row + r) * N + col] = v;
            }
        }
    }
}

// ---------------------------------------------------------------- RoPE (in-place on QKV) + k output
// QKV: [S][6144] bf16 ; cols 0..4095 = Q (32 heads), 4096..5119 = K (8 kv heads)
__global__ void rope_qk(bf16_t* __restrict__ QKV, float* __restrict__ k_out, int S)
{
    int idx  = blockIdx.x * 256 + threadIdx.x;   // over S*64
    int d    = idx & 63;
    int s    = idx >> 6;
    int head = blockIdx.y;                       // 0..39 (0..31 Q, 32..39 K)
    float ang = (float)s * exp2f((float)d * -0.20762050593f);  // log2(10000)/64
    float sn, cs;
    sincosf(ang, &sn, &cs);
    int col = head < 32 ? head * 128 : 4096 + (head - 32) * 128;
    bf16_t* p = QKV + (size_t)s * 6144 + col;
    float x1 = (float)p[d], x2 = (float)p[d + 64];
    float y1 = x1 * cs - x2 * sn;
    float y2 = x2 * cs + x1 * sn;
    p[d]      = (bf16_t)y1;
    p[d + 64] = (bf16_t)y2;
    if (head >= 32) {
        int g = head - 32;
        #pragma unroll
        for (int j = 0; j < 4; ++j) {            // repeat_interleave x4
            float* kb = k_out + ((size_t)(g * 4 + j) * S + s) * 128;
            kb[d]      = y1;
            kb[d + 64] = y2;
        }
    }
}

// ---------------------------------------------------------------- v output + V^T build
// QKV cols 5120..6143 = V. v_out: [32][S][128] fp32 ; Vt: [1024][S] bf16
__global__ void v_finish(const bf16_t* __restrict__ QKV, float* __restrict__ v_out,
                         bf16_t* __restrict__ Vt, int S)
{
    __shared__ bf16_t tl[32][33];
    const int s0  = blockIdx.x * 32;
    const int gd0 = blockIdx.y * 32;
    const int r = threadIdx.x >> 5;
    const int c = threadIdx.x & 31;
    #pragma unroll
    for (int i = 0; i < 32; i += 8) {
        int s = s0 + r + i;
        bf16_t v = QKV[(size_t)s * 6144 + 5120 + gd0 + c];
        tl[r + i][c] = v;
        int gd = gd0 + c;
        int g = gd >> 7, d = gd & 127;
        float vf = (float)v;
        #pragma unroll
        for (int j = 0; j < 4; ++j)
            v_out[((size_t)(g * 4 + j) * S + s) * 128 + d] = vf;
    }
    __syncthreads();
    #pragma unroll
    for (int i = 0; i < 32; i += 8)
        Vt[(size_t)(gd0 + r + i) * S + s0 + c] = tl[c][r + i];
}

// ---------------------------------------------------------------- fragment packer
// Repack K (rope'd, from QKV) and V^T (from Vt) into MFMA-fragment-contiguous
// layouts so the attention inner loop issues only fully-coalesced 1KB loads.
__global__ void pack_frags(const bf16_t* __restrict__ QKV, const bf16_t* __restrict__ Vt,
                           bf16_t* __restrict__ Kfrag, bf16_t* __restrict__ Vfrag, int S)
{
    const int b  = blockIdx.x;        // 256 tiles: g = b>>5, kt = b&31
    const int g  = b >> 5, kt = b & 31;
    const int t  = threadIdx.x;
    bf16x8* Kf = (bf16x8*)Kfrag + (size_t)b * 1024;
    bf16x8* Vf = (bf16x8*)Vfrag + (size_t)b * 1024;
    #pragma unroll
    for (int i = 0; i < 4; ++i) {     // K: 1024 granule slots
        int slot = i * 256 + t;
        int f = slot >> 6, l = slot & 63;
        int kk = f >> 2, nt = f & 3, lm = l & 15, lq = l >> 4;
        Kf[slot] = *(const bf16x8*)(QKV + (size_t)(kt * 64 + nt * 16 + lm) * 6144
                                    + 4096 + g * 128 + kk * 32 + lq * 8);
    }
    #pragma unroll
    for (int i = 0; i < 4; ++i) {     // V: 1024 granule slots
        int slot = i * 256 + t;
        int f = slot >> 6, l = slot & 63;
        int kk = f >> 3, nt = f & 7, lm = l & 15, lq = l >> 4;
        Vf[slot] = *(const bf16x8*)(Vt + (size_t)(g * 128 + nt * 16 + lm) * S
                                    + kt * 64 + kk * 32 + lq * 8);
    }
}

// ---------------------------------------------------------------- flash attention (causal, split-K x4)
// One block per (head, 32 q-rows); FOUR waves split the key-tile range
// (wave w handles kt = w, w+4, ...), each with private online-softmax state.
// LDS combine at the end. __launch_bounds__(256, 2): unified VGPR+AGPR cap 256.
// XCD GROUPING (R7): task decode g = blockIdx.x & 7 puts all blocks of one
// kv-group on one XCD (round-robin dispatch) -> per-XCD K/V frag working set
// 2 MB < 4 MB L2; the ~1.1 GB of frag re-reads become L2 hits instead of L3.
// LDS LIFETIME LEDGER (R5 NaN fix): ml has its OWN region [18432,19456) --
// written pre-barrier, overlaps no P buffer. Cb aliases P but is only touched
// after the first __syncthreads() (all K-loops complete).
__global__ __launch_bounds__(256, 2)
void attn_fwd(const bf16_t* __restrict__ QKV,
              const bf16_t* __restrict__ Kfrag, const bf16_t* __restrict__ Vfrag,
              bf16_t* __restrict__ O, int S)
{
    const int b    = blockIdx.x;                 // 2048 tasks
    const int g    = b & 7;                      // kv-group == XCD (b%8 dispatch)
    const int idx  = b >> 3;                     // 0..255 within group
    const int h    = g * 4 + (idx & 3);
    const int c    = 63 - (idx >> 2);            // q-chunk, heavy-first dispatch
    const int wave = threadIdx.x >> 6;           // 0..3 key-split
    const int lane = threadIdx.x & 63;
    const int lm   = lane & 15;
    const int lq   = lane >> 4;
    const int q0   = c * 32;

    // [0,18432): per-wave P buffers (4 x 32x72 bf16), aliased by Cb[32][132] f32
    // after the first barrier. [18432,19456): ml[4][2][32] f32 (non-aliased).
    __shared__ __align__(16) char smem[19456];
    bf16_t* P  = (bf16_t*)smem + wave * (32 * 72);
    float*  Cb = (float*)smem;                   // [32][132]
    float*  ml = (float*)(smem + 18432);         // [w][{m,l}][row]

    // Q fragments resident in registers (A-layout): 2 m-tiles x 4 k-chunks
    bf16x8 aq[2][4];
    #pragma unroll
    for (int mi = 0; mi < 2; ++mi) {
        const bf16_t* qrow = QKV + (size_t)(q0 + mi * 16 + lm) * 6144 + h * 128;
        #pragma unroll
        for (int kk = 0; kk < 4; ++kk)
            aq[mi][kk] = *(const bf16x8*)(qrow + kk * 32 + lq * 8);
    }

    f32x4 acc[2][8] = {};
    float mrow[2][4], lrow[2][4];
    #pragma unroll
    for (int mi = 0; mi < 2; ++mi)
        #pragma unroll
        for (int r = 0; r < 4; ++r) { mrow[mi][r] = -3.0e38f; lrow[mi][r] = 0.f; }
    const float scale = 0.08838834764831845f;    // 1/sqrt(128)

    const int nkt = (q0 >> 6) + 1;

    for (int kt = wave; kt < nkt; kt += 4) {
        const int k0 = kt * 64;
        const bf16x8* Kf = (const bf16x8*)Kfrag + ((size_t)(g * 32 + kt) << 10);
        const bf16x8* Vf = (const bf16x8*)Vfrag + ((size_t)(g * 32 + kt) << 10);

        // K fragments: coalesced
        bf16x8 bk[4][4];                          // [kk][nt]
        #pragma unroll
        for (int kk = 0; kk < 4; ++kk)
            #pragma unroll
            for (int nt = 0; nt < 4; ++nt)
                bk[kk][nt] = Kf[(kk * 4 + nt) * 64 + lane];

        f32x4 sc[2][4] = {};
        #pragma unroll
        for (int kk = 0; kk < 4; ++kk)
            #pragma unroll
            for (int nt = 0; nt < 4; ++nt)
                #pragma unroll
                for (int mi = 0; mi < 2; ++mi)
                    sc[mi][nt] = __builtin_amdgcn_mfma_f32_16x16x32_bf16(
                        aq[mi][kk], bk[kk][nt], sc[mi][nt], 0, 0, 0);

        // V^T fragments: issue now so they overlap the softmax VALU work
        bf16x8 bv[2][8];                          // [kk][nt]
        #pragma unroll
        for (int kk = 0; kk < 2; ++kk)
            #pragma unroll
            for (int nt = 0; nt < 8; ++nt)
                bv[kk][nt] = Vf[(kk * 8 + nt) * 64 + lane];

        #pragma unroll
        for (int mi = 0; mi < 2; ++mi)
            #pragma unroll
            for (int nt = 0; nt < 4; ++nt)
                #pragma unroll
                for (int r = 0; r < 4; ++r)
                    sc[mi][nt][r] *= scale;

        if (kt == nkt - 1) {                      // causal mask on final tile
            #pragma unroll
            for (int mi = 0; mi < 2; ++mi)
                #pragma unroll
                for (int nt = 0; nt < 4; ++nt) {
                    int col = k0 + nt * 16 + lm;
                    #pragma unroll
                    for (int r = 0; r < 4; ++r) {
                        int row = q0 + mi * 16 + lq * 4 + r;
                        if (col > row) sc[mi][nt][r] = -3.0e38f;
                    }
                }
        }

        // online softmax (row lives across the 16 lm-lanes of an lq-group)
        #pragma unroll
        for (int mi = 0; mi < 2; ++mi) {
            float tmax[4];
            #pragma unroll
            for (int r = 0; r < 4; ++r)
                tmax[r] = fmaxf(fmaxf(sc[mi][0][r], sc[mi][1][r]),
                                fmaxf(sc[mi][2][r], sc[mi][3][r]));
            #pragma unroll
            for (int off = 1; off < 16; off <<= 1)
                #pragma unroll
                for (int r = 0; r < 4; ++r)
                    tmax[r] = fmaxf(tmax[r], __shfl_xor(tmax[r], off));

            float alpha[4];
            #pragma unroll
            for (int r = 0; r < 4; ++r) {
                float mn = fmaxf(mrow[mi][r], tmax[r]);
                alpha[r] = __expf(mrow[mi][r] - mn);
                mrow[mi][r] = mn;
            }
            float rsum[4] = {0.f, 0.f, 0.f, 0.f};
            #pragma unroll
            for (int nt = 0; nt < 4; ++nt)
                #pragma unroll
                for (int r = 0; r < 4; ++r) {
                    float p = __expf(sc[mi][nt][r] - mrow[mi][r]);
                    sc[mi][nt][r] = p;
                    rsum[r] += p;
                }
            #pragma unroll
            for (int off = 1; off < 16; off <<= 1)
                #pragma unroll
                for (int r = 0; r < 4; ++r)
                    rsum[r] += __shfl_xor(rsum[r], off);
            #pragma unroll
            for (int r = 0; r < 4; ++r)
                lrow[mi][r] = lrow[mi][r] * alpha[r] + rsum[r];
            #pragma unroll
            for (int nt = 0; nt < 8; ++nt)
                #pragma unroll
                for (int r = 0; r < 4; ++r)
                    acc[mi][nt][r] *= alpha[r];

            // P: C-layout -> LDS (per-wave buffer, wave-internal)
            #pragma unroll
            for (int nt = 0; nt < 4; ++nt)
                #pragma unroll
                for (int r = 0; r < 4; ++r)
                    P[(mi * 16 + lq * 4 + r) * 72 + nt * 16 + lm] = (bf16_t)sc[mi][nt][r];
        }

        // P: LDS -> A-layout (wave-internal; compiler inserts lgkmcnt wait)
        bf16x8 ap[2][2];
        #pragma unroll
        for (int mi = 0; mi < 2; ++mi)
            #pragma unroll
            for (int kk = 0; kk < 2; ++kk)
                ap[mi][kk] = *(const bf16x8*)(P + (mi * 16 + lm) * 72 + kk * 32 + lq * 8);

        #pragma unroll
        for (int kk = 0; kk < 2; ++kk)
            #pragma unroll
            for (int nt = 0; nt < 8; ++nt)
                #pragma unroll
                for (int mi = 0; mi < 2; ++mi)
                    acc[mi][nt] = __builtin_amdgcn_mfma_f32_16x16x32_bf16(
                        ap[mi][kk], bv[kk][nt], acc[mi][nt], 0, 0, 0);
    }

    // -------- cross-wave combine --------
    // publish per-row m,l into the DEDICATED ml region (safe pre-barrier:
    // each wave writes only its own slots, region overlaps no P buffer)
    if (lm == 0) {
        #pragma unroll
        for (int mi = 0; mi < 2; ++mi)
            #pragma unroll
            for (int r = 0; r < 4; ++r) {
                int lr = mi * 16 + lq * 4 + r;
                ml[(wave * 2 + 0) * 32 + lr] = mrow[mi][r];
                ml[(wave * 2 + 1) * 32 + lr] = lrow[mi][r];
            }
    }
    __syncthreads();

    float fac[2][4], linv[2][4];
    #pragma unroll
    for (int mi = 0; mi < 2; ++mi)
        #pragma unroll
        for (int r = 0; r < 4; ++r) {
            int lr = mi * 16 + lq * 4 + r;
            float m0 = ml[0 * 32 + lr], m1 = ml[2 * 32 + lr];
            float m2 = ml[4 * 32 + lr], m3 = ml[6 * 32 + lr];
            float mg = fmaxf(fmaxf(m0, m1), fmaxf(m2, m3));
            float ls = ml[1 * 32 + lr] * __expf(m0 - mg)
                     + ml[3 * 32 + lr] * __expf(m1 - mg)
                     + ml[5 * 32 + lr] * __expf(m2 - mg)
                     + ml[7 * 32 + lr] * __expf(m3 - mg);
            fac[mi][r]  = __expf(mrow[mi][r] - mg);
            linv[mi][r] = 1.0f / ls;
        }

    // sequential f32 accumulation: waves 0..2 into Cb, wave 3 reads+adds+writes O
    for (int w = 0; w < 3; ++w) {
        if (wave == w) {
            #pragma unroll
            for (int mi = 0; mi < 2; ++mi)
                #pragma unroll
                for (int nt = 0; nt < 8; ++nt)
                    #pragma unroll
                    for (int r = 0; r < 4; ++r) {
                        int lr = mi * 16 + lq * 4 + r;
                        int col = nt * 16 + lm;
                        float v = acc[mi][nt][r] * fac[mi][r];
                        if (w == 0) Cb[lr * 132 + col] = v;
                        else        Cb[lr * 132 + col] += v;
                    }
        }
        __syncthreads();
    }
    if (wave == 3) {
        #pragma unroll
        for (int mi = 0; mi < 2; ++mi)
            #pragma unroll
            for (int nt = 0; nt < 8; ++nt)
                #pragma unroll
                for (int r = 0; r < 4; ++r) {
                    int lr = mi * 16 + lq * 4 + r;
                    int col = nt * 16 + lm;
                    float v = Cb[lr * 132 + col] + acc[mi][nt][r] * fac[mi][r];
                    O[(size_t)(q0 + lr) * 4096 + h * 128 + col] =
                        (bf16_t)(v * linv[mi][r]);
                }
    }
}

// ---------------------------------------------------------------- launch
extern "C" void kernel_launch(void* const* d_in, const int* in_sizes, int n_in,
                              void* d_out, int out_size, void* d_ws, size_t ws_size,
                              hipStream_t stream)
{
    const float* hidden = (const float*)d_in[0];
    const float* Wq = (const float*)d_in[1];
    const float* Wk = (const float*)d_in[2];
    const float* Wv = (const float*)d_in[3];
    const float* Wo = (const float*)d_in[4];

    const int S = 2048, H = 4096, KV = 1024, NQKV = 6144;

    // workspace layout (total ~140 MB)
    char* ws = (char*)d_ws;
    bf16_t* hid_b  = (bf16_t*)(ws);                         // S*H bf16      = 16 MB
    bf16_t* Wqkv_t = (bf16_t*)(ws + (size_t)(16u  << 20));  // 6144*4096 bf16= 48 MB
    bf16_t* Wo_t   = (bf16_t*)(ws + (size_t)(64u  << 20));  // 4096*4096 bf16= 32 MB
    bf16_t* QKV    = (bf16_t*)(ws + (size_t)(96u  << 20));  // S*6144 bf16   = 24 MB
    bf16_t* Vt     = (bf16_t*)(ws + (size_t)(120u << 20));  // 1024*S bf16   =  4 MB
    bf16_t* attn   = (bf16_t*)(ws + (size_t)(124u << 20));  // S*H bf16      = 16 MB
    // Kfrag/Vfrag reuse hid_b's region (dead after the QKV GEMM): 4 MB + 4 MB
    bf16_t* Kfrag  = (bf16_t*)(ws);
    bf16_t* Vfrag  = (bf16_t*)(ws + (size_t)(4u << 20));

    float* out_o = (float*)d_out;                 // [S][H]
    float* out_k = out_o + (size_t)S * H;         // [32][S][128]
    float* out_v = out_k + (size_t)32 * S * 128;  // [32][S][128]

    convert_f32_bf16<<<S * H / 4 / 256, 256, 0, stream>>>(hidden, hid_b);
    transpose_convert<<<dim3(H / 32, H / 32), 256, 0, stream>>>(Wq, Wqkv_t, H, H);
    transpose_convert<<<dim3(KV / 32, H / 32), 256, 0, stream>>>(Wk, Wqkv_t + (size_t)4096 * H, H, KV);
    transpose_convert<<<dim3(KV / 32, H / 32), 256, 0, stream>>>(Wv, Wqkv_t + (size_t)5120 * H, H, KV);
    transpose_convert<<<dim3(H / 32, H / 32), 256, 0, stream>>>(Wo, Wo_t, H, H);

    gemm_bt_128<bf16_t><<<dim3(S / 128, NQKV / 128), 256, 0, stream>>>(hid_b, Wqkv_t, QKV, S, NQKV, H);

    rope_qk<<<dim3(S * 64 / 256, 40), 256, 0, stream>>>(QKV, out_k, S);
    v_finish<<<dim3(S / 32, KV / 32), 256, 0, stream>>>(QKV, out_v, Vt, S);
    pack_frags<<<256, 256, 0, stream>>>(QKV, Vt, Kfrag, Vfrag, S);

    attn_fwd<<<2048, 256, 0, stream>>>(QKV, Kfrag, Vfrag, attn, S);

    gemm_bt_128<float><<<dim3(S / 128, H / 128), 256, 0, stream>>>(attn, Wo_t, out_o, S, H, H);
}

// Round 8
// 562.527 us; speedup vs baseline: 1.5986x; 1.0596x over previous
//
#include <hip/hip_runtime.h>
#include <hip/hip_bf16.h>
#include <math.h>

typedef __bf16 bf16_t;
typedef bf16_t bf16x8 __attribute__((ext_vector_type(8)));
typedef bf16_t bf16x4 __attribute__((ext_vector_type(4)));
typedef float  f32x4  __attribute__((ext_vector_type(4)));

#define AS1(p) ((__attribute__((address_space(1))) void*)(p))
#define AS3(p) ((__attribute__((address_space(3))) void*)(p))

// ---------------------------------------------------------------- converts
__global__ void convert_f32_bf16(const float* __restrict__ in, bf16_t* __restrict__ out)
{
    int i = blockIdx.x * 256 + threadIdx.x;
    float4 v = ((const float4*)in)[i];
    bf16x4 o;
    o[0] = (bf16_t)v.x; o[1] = (bf16_t)v.y; o[2] = (bf16_t)v.z; o[3] = (bf16_t)v.w;
    ((bf16x4*)out)[i] = o;
}

// W: [K][N] fp32 row-major  ->  Wt: [N][K] bf16 row-major
__global__ void transpose_convert(const float* __restrict__ W, bf16_t* __restrict__ Wt,
                                  int K, int N)
{
    __shared__ float tile[32][33];
    const int n0 = blockIdx.x * 32;
    const int k0 = blockIdx.y * 32;
    const int r = threadIdx.x >> 5;
    const int c = threadIdx.x & 31;
    #pragma unroll
    for (int i = 0; i < 32; i += 8)
        tile[r + i][c] = W[(size_t)(k0 + r + i) * N + n0 + c];
    __syncthreads();
    #pragma unroll
    for (int i = 0; i < 32; i += 8)
        Wt[(size_t)(n0 + r + i) * K + k0 + c] = (bf16_t)tile[c][r + i];
}

// ---------------------------------------------------------------- GEMM (m97 structure, BK=64, swizzled)
// C[M][N] = A[M][K] @ Bt[N][K]^T ; bf16 ; 128x128 tile, BK=64, 256 thr / 4 waves.
// BK=64 halves the barrier-pair count vs BK=32 (the vmcnt+lgkm drain before
// s_barrier is the structural ~20% stall of this 2-phase loop).
// LDS XOR-granule swizzle (both-sides, R1-verified 0 conflicts): LDS row r,
// granule gl holds GLOBAL granule gl^(r&7); staging reads source col
// ((tid&7)^(sr&7))*8 into a LINEAR gload_lds dest; ds_read uses granule
// (kk*4+lq)^(lm&7). Without it BK=64's 128B row stride is a 16-way conflict.
// T1 bijective chunked XCD swizzle (nwg%8==0 at both call sites: 768, 512).
template <typename OutT>
__global__ __launch_bounds__(256)
void gemm_bt_128(const bf16_t* __restrict__ A, const bf16_t* __restrict__ Bt,
                 OutT* __restrict__ C, int M, int N, int K)
{
    __shared__ bf16_t As[128 * 64];
    __shared__ bf16_t Bs[128 * 64];
    const int t    = threadIdx.x;
    const int lane = t & 63;
    const int wave = t >> 6;

    const int nwg   = gridDim.x * gridDim.y;
    int bid = blockIdx.x + blockIdx.y * gridDim.x;
    const int chunk = nwg >> 3;                   // nwg % 8 == 0
    bid = (bid & 7) * chunk + (bid >> 3);
    const int m0 = (bid % gridDim.x) * 128;
    const int n0 = (bid / gridDim.x) * 128;

    const int wm = (wave & 1) * 64;
    const int wn = (wave >> 1) * 64;
    const int lm = lane & 15;
    const int lq = lane >> 4;

    f32x4 acc[4][4] = {};

    // staging: thread covers LDS slot (i*256+tid), i=0..3 -> row i*32+sr,
    // granule tid&7; source col inverse-swizzled so LDS gl holds gs=gl^(r&7)
    const int sr = t >> 3;                        // 0..31
    const int sg = ((t & 7) ^ (sr & 7)) * 8;      // swizzled source col (elems)
    const bf16_t* Ag = A  + (size_t)(m0 + sr) * K + sg;
    const bf16_t* Bg = Bt + (size_t)(n0 + sr) * K + sg;
    bf16_t* AsW = As + wave * 512;                // wave-uniform LDS base (+i*2048)
    bf16_t* BsW = Bs + wave * 512;

    for (int k0 = 0; k0 < K; k0 += 64) {
        __syncthreads();
        #pragma unroll
        for (int i = 0; i < 4; ++i) {
            __builtin_amdgcn_global_load_lds(AS1(Ag + (size_t)(i * 32) * K + k0),
                                             AS3(AsW + i * 2048), 16, 0, 0);
            __builtin_amdgcn_global_load_lds(AS1(Bg + (size_t)(i * 32) * K + k0),
                                             AS3(BsW + i * 2048), 16, 0, 0);
        }
        __syncthreads();

        #pragma unroll
        for (int kk = 0; kk < 2; ++kk) {
            bf16x8 af[4], bb[4];
            #pragma unroll
            for (int mt = 0; mt < 4; ++mt)
                af[mt] = *(const bf16x8*)(As + (wm + mt * 16 + lm) * 64
                                          + (((kk * 4 + lq) ^ (lm & 7)) * 8));
            #pragma unroll
            for (int nt = 0; nt < 4; ++nt)
                bb[nt] = *(const bf16x8*)(Bs + (wn + nt * 16 + lm) * 64
                                          + (((kk * 4 + lq) ^ (lm & 7)) * 8));
            #pragma unroll
            for (int mt = 0; mt < 4; ++mt)
                #pragma unroll
                for (int nt = 0; nt < 4; ++nt)
                    acc[mt][nt] = __builtin_amdgcn_mfma_f32_16x16x32_bf16(
                        af[mt], bb[nt], acc[mt][nt], 0, 0, 0);
        }
    }

    #pragma unroll
    for (int mt = 0; mt < 4; ++mt) {
        #pragma unroll
        for (int nt = 0; nt < 4; ++nt) {
            const int row = m0 + wm + mt * 16 + lq * 4;
            const int col = n0 + wn + nt * 16 + lm;
            #pragma unroll
            for (int r = 0; r < 4; ++r) {
                float v = acc[mt][nt][r];
                if constexpr (sizeof(OutT) == 2)
                    C[(size_t)(row + r) * N + col] = (OutT)(bf16_t)v;
                else
                    C[(size_t)(row + r) * N + col] = v;
            }
        }
    }
}

// ---------------------------------------------------------------- RoPE (in-place on QKV) + k output
// QKV: [S][6144] bf16 ; cols 0..4095 = Q (32 heads), 4096..5119 = K (8 kv heads)
__global__ void rope_qk(bf16_t* __restrict__ QKV, float* __restrict__ k_out, int S)
{
    int idx  = blockIdx.x * 256 + threadIdx.x;   // over S*64
    int d    = idx & 63;
    int s    = idx >> 6;
    int head = blockIdx.y;                       // 0..39 (0..31 Q, 32..39 K)
    float ang = (float)s * exp2f((float)d * -0.20762050593f);  // log2(10000)/64
    float sn, cs;
    sincosf(ang, &sn, &cs);
    int col = head < 32 ? head * 128 : 4096 + (head - 32) * 128;
    bf16_t* p = QKV + (size_t)s * 6144 + col;
    float x1 = (float)p[d], x2 = (float)p[d + 64];
    float y1 = x1 * cs - x2 * sn;
    float y2 = x2 * cs + x1 * sn;
    p[d]      = (bf16_t)y1;
    p[d + 64] = (bf16_t)y2;
    if (head >= 32) {
        int g = head - 32;
        #pragma unroll
        for (int j = 0; j < 4; ++j) {            // repeat_interleave x4
            float* kb = k_out + ((size_t)(g * 4 + j) * S + s) * 128;
            kb[d]      = y1;
            kb[d + 64] = y2;
        }
    }
}

// ---------------------------------------------------------------- v output + V^T build
// QKV cols 5120..6143 = V. v_out: [32][S][128] fp32 ; Vt: [1024][S] bf16
__global__ void v_finish(const bf16_t* __restrict__ QKV, float* __restrict__ v_out,
                         bf16_t* __restrict__ Vt, int S)
{
    __shared__ bf16_t tl[32][33];
    const int s0  = blockIdx.x * 32;
    const int gd0 = blockIdx.y * 32;
    const int r = threadIdx.x >> 5;
    const int c = threadIdx.x & 31;
    #pragma unroll
    for (int i = 0; i < 32; i += 8) {
        int s = s0 + r + i;
        bf16_t v = QKV[(size_t)s * 6144 + 5120 + gd0 + c];
        tl[r + i][c] = v;
        int gd = gd0 + c;
        int g = gd >> 7, d = gd & 127;
        float vf = (float)v;
        #pragma unroll
        for (int j = 0; j < 4; ++j)
            v_out[((size_t)(g * 4 + j) * S + s) * 128 + d] = vf;
    }
    __syncthreads();
    #pragma unroll
    for (int i = 0; i < 32; i += 8)
        Vt[(size_t)(gd0 + r + i) * S + s0 + c] = tl[c][r + i];
}

// ---------------------------------------------------------------- fragment packer
// Repack K (rope'd, from QKV) and V^T (from Vt) into MFMA-fragment-contiguous
// layouts so the attention inner loop issues only fully-coalesced 1KB loads.
__global__ void pack_frags(const bf16_t* __restrict__ QKV, const bf16_t* __restrict__ Vt,
                           bf16_t* __restrict__ Kfrag, bf16_t* __restrict__ Vfrag, int S)
{
    const int b  = blockIdx.x;        // 256 tiles: g = b>>5, kt = b&31
    const int g  = b >> 5, kt = b & 31;
    const int t  = threadIdx.x;
    bf16x8* Kf = (bf16x8*)Kfrag + (size_t)b * 1024;
    bf16x8* Vf = (bf16x8*)Vfrag + (size_t)b * 1024;
    #pragma unroll
    for (int i = 0; i < 4; ++i) {     // K: 1024 granule slots
        int slot = i * 256 + t;
        int f = slot >> 6, l = slot & 63;
        int kk = f >> 2, nt = f & 3, lm = l & 15, lq = l >> 4;
        Kf[slot] = *(const bf16x8*)(QKV + (size_t)(kt * 64 + nt * 16 + lm) * 6144
                                    + 4096 + g * 128 + kk * 32 + lq * 8);
    }
    #pragma unroll
    for (int i = 0; i < 4; ++i) {     // V: 1024 granule slots
        int slot = i * 256 + t;
        int f = slot >> 6, l = slot & 63;
        int kk = f >> 3, nt = f & 7, lm = l & 15, lq = l >> 4;
        Vf[slot] = *(const bf16x8*)(Vt + (size_t)(g * 128 + nt * 16 + lm) * S
                                    + kt * 64 + kk * 32 + lq * 8);
    }
}

// ---------------------------------------------------------------- flash attention (causal, split-K x4)
// One block per (head, 32 q-rows); FOUR waves split the key-tile range
// (wave w handles kt = w, w+4, ...), each with private online-softmax state.
// LDS combine at the end. __launch_bounds__(256, 2): unified VGPR+AGPR cap 256.
// XCD GROUPING: g = blockIdx.x & 7 -> one kv-group per XCD (L2-resident frags).
// LDS LIFETIME LEDGER: ml has its OWN region [18432,19456) -- written
// pre-barrier, overlaps no P buffer. Cb aliases P but is only touched after
// the first __syncthreads() (all K-loops complete).
__global__ __launch_bounds__(256, 2)
void attn_fwd(const bf16_t* __restrict__ QKV,
              const bf16_t* __restrict__ Kfrag, const bf16_t* __restrict__ Vfrag,
              bf16_t* __restrict__ O, int S)
{
    const int b    = blockIdx.x;                 // 2048 tasks
    const int g    = b & 7;                      // kv-group == XCD (b%8 dispatch)
    const int idx  = b >> 3;                     // 0..255 within group
    const int h    = g * 4 + (idx & 3);
    const int c    = 63 - (idx >> 2);            // q-chunk, heavy-first dispatch
    const int wave = threadIdx.x >> 6;           // 0..3 key-split
    const int lane = threadIdx.x & 63;
    const int lm   = lane & 15;
    const int lq   = lane >> 4;
    const int q0   = c * 32;

    // [0,18432): per-wave P buffers (4 x 32x72 bf16), aliased by Cb[32][132] f32
    // after the first barrier. [18432,19456): ml[4][2][32] f32 (non-aliased).
    __shared__ __align__(16) char smem[19456];
    bf16_t* P  = (bf16_t*)smem + wave * (32 * 72);
    float*  Cb = (float*)smem;                   // [32][132]
    float*  ml = (float*)(smem + 18432);         // [w][{m,l}][row]

    // Q fragments resident in registers (A-layout): 2 m-tiles x 4 k-chunks
    bf16x8 aq[2][4];
    #pragma unroll
    for (int mi = 0; mi < 2; ++mi) {
        const bf16_t* qrow = QKV + (size_t)(q0 + mi * 16 + lm) * 6144 + h * 128;
        #pragma unroll
        for (int kk = 0; kk < 4; ++kk)
            aq[mi][kk] = *(const bf16x8*)(qrow + kk * 32 + lq * 8);
    }

    f32x4 acc[2][8] = {};
    float mrow[2][4], lrow[2][4];
    #pragma unroll
    for (int mi = 0; mi < 2; ++mi)
        #pragma unroll
        for (int r = 0; r < 4; ++r) { mrow[mi][r] = -3.0e38f; lrow[mi][r] = 0.f; }
    const float scale = 0.08838834764831845f;    // 1/sqrt(128)

    const int nkt = (q0 >> 6) + 1;

    for (int kt = wave; kt < nkt; kt += 4) {
        const int k0 = kt * 64;
        const bf16x8* Kf = (const bf16x8*)Kfrag + ((size_t)(g * 32 + kt) << 10);
        const bf16x8* Vf = (const bf16x8*)Vfrag + ((size_t)(g * 32 + kt) << 10);

        // K fragments: coalesced
        bf16x8 bk[4][4];                          // [kk][nt]
        #pragma unroll
        for (int kk = 0; kk < 4; ++kk)
            #pragma unroll
            for (int nt = 0; nt < 4; ++nt)
                bk[kk][nt] = Kf[(kk * 4 + nt) * 64 + lane];

        f32x4 sc[2][4] = {};
        #pragma unroll
        for (int kk = 0; kk < 4; ++kk)
            #pragma unroll
            for (int nt = 0; nt < 4; ++nt)
                #pragma unroll
                for (int mi = 0; mi < 2; ++mi)
                    sc[mi][nt] = __builtin_amdgcn_mfma_f32_16x16x32_bf16(
                        aq[mi][kk], bk[kk][nt], sc[mi][nt], 0, 0, 0);

        // V^T fragments: issue now so they overlap the softmax VALU work
        bf16x8 bv[2][8];                          // [kk][nt]
        #pragma unroll
        for (int kk = 0; kk < 2; ++kk)
            #pragma unroll
            for (int nt = 0; nt < 8; ++nt)
                bv[kk][nt] = Vf[(kk * 8 + nt) * 64 + lane];

        #pragma unroll
        for (int mi = 0; mi < 2; ++mi)
            #pragma unroll
            for (int nt = 0; nt < 4; ++nt)
                #pragma unroll
                for (int r = 0; r < 4; ++r)
                    sc[mi][nt][r] *= scale;

        if (kt == nkt - 1) {                      // causal mask on final tile
            #pragma unroll
            for (int mi = 0; mi < 2; ++mi)
                #pragma unroll
                for (int nt = 0; nt < 4; ++nt) {
                    int col = k0 + nt * 16 + lm;
                    #pragma unroll
                    for (int r = 0; r < 4; ++r) {
                        int row = q0 + mi * 16 + lq * 4 + r;
                        if (col > row) sc[mi][nt][r] = -3.0e38f;
                    }
                }
        }

        // online softmax (row lives across the 16 lm-lanes of an lq-group)
        #pragma unroll
        for (int mi = 0; mi < 2; ++mi) {
            float tmax[4];
            #pragma unroll
            for (int r = 0; r < 4; ++r)
                tmax[r] = fmaxf(fmaxf(sc[mi][0][r], sc[mi][1][r]),
                                fmaxf(sc[mi][2][r], sc[mi][3][r]));
            #pragma unroll
            for (int off = 1; off < 16; off <<= 1)
                #pragma unroll
                for (int r = 0; r < 4; ++r)
                    tmax[r] = fmaxf(tmax[r], __shfl_xor(tmax[r], off));

            float alpha[4];
            #pragma unroll
            for (int r = 0; r < 4; ++r) {
                float mn = fmaxf(mrow[mi][r], tmax[r]);
                alpha[r] = __expf(mrow[mi][r] - mn);
                mrow[mi][r] = mn;
            }
            float rsum[4] = {0.f, 0.f, 0.f, 0.f};
            #pragma unroll
            for (int nt = 0; nt < 4; ++nt)
                #pragma unroll
                for (int r = 0; r < 4; ++r) {
                    float p = __expf(sc[mi][nt][r] - mrow[mi][r]);
                    sc[mi][nt][r] = p;
                    rsum[r] += p;
                }
            #pragma unroll
            for (int off = 1; off < 16; off <<= 1)
                #pragma unroll
                for (int r = 0; r < 4; ++r)
                    rsum[r] += __shfl_xor(rsum[r], off);
            #pragma unroll
            for (int r = 0; r < 4; ++r)
                lrow[mi][r] = lrow[mi][r] * alpha[r] + rsum[r];
            #pragma unroll
            for (int nt = 0; nt < 8; ++nt)
                #pragma unroll
                for (int r = 0; r < 4; ++r)
                    acc[mi][nt][r] *= alpha[r];

            // P: C-layout -> LDS (per-wave buffer, wave-internal)
            #pragma unroll
            for (int nt = 0; nt < 4; ++nt)
                #pragma unroll
                for (int r = 0; r < 4; ++r)
                    P[(mi * 16 + lq * 4 + r) * 72 + nt * 16 + lm] = (bf16_t)sc[mi][nt][r];
        }

        // P: LDS -> A-layout (wave-internal; compiler inserts lgkmcnt wait)
        bf16x8 ap[2][2];
        #pragma unroll
        for (int mi = 0; mi < 2; ++mi)
            #pragma unroll
            for (int kk = 0; kk < 2; ++kk)
                ap[mi][kk] = *(const bf16x8*)(P + (mi * 16 + lm) * 72 + kk * 32 + lq * 8);

        #pragma unroll
        for (int kk = 0; kk < 2; ++kk)
            #pragma unroll
            for (int nt = 0; nt < 8; ++nt)
                #pragma unroll
                for (int mi = 0; mi < 2; ++mi)
                    acc[mi][nt] = __builtin_amdgcn_mfma_f32_16x16x32_bf16(
                        ap[mi][kk], bv[kk][nt], acc[mi][nt], 0, 0, 0);
    }

    // -------- cross-wave combine --------
    // publish per-row m,l into the DEDICATED ml region (safe pre-barrier:
    // each wave writes only its own slots, region overlaps no P buffer)
    if (lm == 0) {
        #pragma unroll
        for (int mi = 0; mi < 2; ++mi)
            #pragma unroll
            for (int r = 0; r < 4; ++r) {
                int lr = mi * 16 + lq * 4 + r;
                ml[(wave * 2 + 0) * 32 + lr] = mrow[mi][r];
                ml[(wave * 2 + 1) * 32 + lr] = lrow[mi][r];
            }
    }
    __syncthreads();

    float fac[2][4], linv[2][4];
    #pragma unroll
    for (int mi = 0; mi < 2; ++mi)
        #pragma unroll
        for (int r = 0; r < 4; ++r) {
            int lr = mi * 16 + lq * 4 + r;
            float m0 = ml[0 * 32 + lr], m1 = ml[2 * 32 + lr];
            float m2 = ml[4 * 32 + lr], m3 = ml[6 * 32 + lr];
            float mg = fmaxf(fmaxf(m0, m1), fmaxf(m2, m3));
            float ls = ml[1 * 32 + lr] * __expf(m0 - mg)
                     + ml[3 * 32 + lr] * __expf(m1 - mg)
                     + ml[5 * 32 + lr] * __expf(m2 - mg)
                     + ml[7 * 32 + lr] * __expf(m3 - mg);
            fac[mi][r]  = __expf(mrow[mi][r] - mg);
            linv[mi][r] = 1.0f / ls;
        }

    // sequential f32 accumulation: waves 0..2 into Cb, wave 3 reads+adds+writes O
    for (int w = 0; w < 3; ++w) {
        if (wave == w) {
            #pragma unroll
            for (int mi = 0; mi < 2; ++mi)
                #pragma unroll
                for (int nt = 0; nt < 8; ++nt)
                    #pragma unroll
                    for (int r = 0; r < 4; ++r) {
                        int lr = mi * 16 + lq * 4 + r;
                        int col = nt * 16 + lm;
                        float v = acc[mi][nt][r] * fac[mi][r];
                        if (w == 0) Cb[lr * 132 + col] = v;
                        else        Cb[lr * 132 + col] += v;
                    }
        }
        __syncthreads();
    }
    if (wave == 3) {
        #pragma unroll
        for (int mi = 0; mi < 2; ++mi)
            #pragma unroll
            for (int nt = 0; nt < 8; ++nt)
                #pragma unroll
                for (int r = 0; r < 4; ++r) {
                    int lr = mi * 16 + lq * 4 + r;
                    int col = nt * 16 + lm;
                    float v = Cb[lr * 132 + col] + acc[mi][nt][r] * fac[mi][r];
                    O[(size_t)(q0 + lr) * 4096 + h * 128 + col] =
                        (bf16_t)(v * linv[mi][r]);
                }
    }
}

// ---------------------------------------------------------------- launch
extern "C" void kernel_launch(void* const* d_in, const int* in_sizes, int n_in,
                              void* d_out, int out_size, void* d_ws, size_t ws_size,
                              hipStream_t stream)
{
    const float* hidden = (const float*)d_in[0];
    const float* Wq = (const float*)d_in[1];
    const float* Wk = (const float*)d_in[2];
    const float* Wv = (const float*)d_in[3];
    const float* Wo = (const float*)d_in[4];

    const int S = 2048, H = 4096, KV = 1024, NQKV = 6144;

    // workspace layout (total ~140 MB)
    char* ws = (char*)d_ws;
    bf16_t* hid_b  = (bf16_t*)(ws);                         // S*H bf16      = 16 MB
    bf16_t* Wqkv_t = (bf16_t*)(ws + (size_t)(16u  << 20));  // 6144*4096 bf16= 48 MB
    bf16_t* Wo_t   = (bf16_t*)(ws + (size_t)(64u  << 20));  // 4096*4096 bf16= 32 MB
    bf16_t* QKV    = (bf16_t*)(ws + (size_t)(96u  << 20));  // S*6144 bf16   = 24 MB
    bf16_t* Vt     = (bf16_t*)(ws + (size_t)(120u << 20));  // 1024*S bf16   =  4 MB
    bf16_t* attn   = (bf16_t*)(ws + (size_t)(124u << 20));  // S*H bf16      = 16 MB
    // Kfrag/Vfrag reuse hid_b's region (dead after the QKV GEMM): 4 MB + 4 MB
    bf16_t* Kfrag  = (bf16_t*)(ws);
    bf16_t* Vfrag  = (bf16_t*)(ws + (size_t)(4u << 20));

    float* out_o = (float*)d_out;                 // [S][H]
    float* out_k = out_o + (size_t)S * H;         // [32][S][128]
    float* out_v = out_k + (size_t)32 * S * 128;  // [32][S][128]

    convert_f32_bf16<<<S * H / 4 / 256, 256, 0, stream>>>(hidden, hid_b);
    transpose_convert<<<dim3(H / 32, H / 32), 256, 0, stream>>>(Wq, Wqkv_t, H, H);
    transpose_convert<<<dim3(KV / 32, H / 32), 256, 0, stream>>>(Wk, Wqkv_t + (size_t)4096 * H, H, KV);
    transpose_convert<<<dim3(KV / 32, H / 32), 256, 0, stream>>>(Wv, Wqkv_t + (size_t)5120 * H, H, KV);
    transpose_convert<<<dim3(H / 32, H / 32), 256, 0, stream>>>(Wo, Wo_t, H, H);

    gemm_bt_128<bf16_t><<<dim3(S / 128, NQKV / 128), 256, 0, stream>>>(hid_b, Wqkv_t, QKV, S, NQKV, H);

    rope_qk<<<dim3(S * 64 / 256, 40), 256, 0, stream>>>(QKV, out_k, S);
    v_finish<<<dim3(S / 32, KV / 32), 256, 0, stream>>>(QKV, out_v, Vt, S);
    pack_frags<<<256, 256, 0, stream>>>(QKV, Vt, Kfrag, Vfrag, S);

    attn_fwd<<<2048, 256, 0, stream>>>(QKV, Kfrag, Vfrag, attn, S);

    gemm_bt_128<float><<<dim3(S / 128, H / 128), 256, 0, stream>>>(attn, Wo_t, out_o, S, H, H);
}